// Round 9
// baseline (548.642 us; speedup 1.0000x reference)
//
#include <hip/hip_runtime.h>

// RPN forward on gfx950. R8: ONE regular kernel (cooperative API fails under graph
// capture — R7) with MANUAL spin grid-barriers. 1024 blocks @ 4/CU (guaranteed
// co-resident: 256 thr, <=128 VGPR via launch_bounds(256,4), 32KB LDS).
// Barrier counters start at the harness's 0xAA ws-poison; wrap-safe compare; bounded spin.
// Phases: P0 prep -> bar -> P1 conv (16x16x32, LDS-roofline ~72us, 0 conflicts) -> bar ->
// P2 heads GEMM + assignment. Numerics identical to R6 (expect absmax 28.125).

typedef __bf16 bf16x8 __attribute__((ext_vector_type(8)));
typedef float floatx4 __attribute__((ext_vector_type(4)));

#define NB 4
#define NC 2048
#define NH 32
#define NW 32
#define NHID 512
#define NA 9
#define NG 20
#define NANC 9216
#define NM 4096
#define NSPLIT 8
#define CSPLIT 256            // NC / NSPLIT

// workspace layout (bytes)
#define OFF_XH    0ull            // [4][34][34][2048] bf16 (zero halo) = 18939904
#define OFF_WT    18939904ull     // [9][512][2048]    bf16 = 18874368
#define OFF_WH    37814272ull     // [48][512]         bf16
#define OFF_HB    37863424ull     // [48] f32 (pad 256)
#define OFF_MAXG  37863680ull     // [4][20] uint (pad 512)
#define OFF_SUMS  37864192ull     // [2] f32 (pad 128)
#define OFF_CTR   37864320ull     // [1] uint (pad 128)
#define OFF_HIDP  37864448ull     // [8][4096][512] bf16 = 33554432
#define OFF_BAR   71418880ull     // [2] uint spin-barrier counters (poison-based)

#define POISON 0xAAAAAAAAu

__device__ __forceinline__ unsigned short f2bf(float f) {
  unsigned int u = __float_as_uint(f);
  u = (u + 0x7fffu + ((u >> 16) & 1u)) >> 16;   // RNE
  return (unsigned short)u;
}

__device__ __forceinline__ void gload16(const void* g, void* l) {
  __builtin_amdgcn_global_load_lds(
      (const __attribute__((address_space(1))) unsigned int*)g,
      (__attribute__((address_space(3))) unsigned int*)l, 16, 0, 0);
}

// grid-wide barrier: all 1024 blocks co-resident (4/CU), so arrival is guaranteed.
// Counter starts at ws-poison 0xAAAAAAAA; wrap-safe compare; bounded spin (no hang).
__device__ __forceinline__ void gbar(unsigned int* bar) {
  __syncthreads();
  if (threadIdx.x == 0) {
    __threadfence();                       // release: L2 writeback (agent scope)
    atomicAdd(bar, 1u);
    int spins = 0;
    while ((atomicAdd(bar, 0u) - POISON) < 1024u) {
      __builtin_amdgcn_s_sleep(8);
      if (++spins > 4000000) break;        // fail visibly, never hang
    }
    __threadfence();                       // acquire: cache invalidate
  }
  __syncthreads();
}

__constant__ float c_aw[9] = {2.f,2.f,2.f,4.f,4.f,4.f,6.f,6.f,6.f};
__constant__ float c_ah[9] = {1.f,2.f,3.f,2.f,4.f,6.f,3.f,6.f,9.f};

// ---- strict-f32 anchor/IoU helpers (bit-identical across phases) ----
struct Anc { float x1, y1, x2, y2, areaA; };
__device__ __forceinline__ Anc anc_of(int n) {
  const int a = n % 9, pix = n / 9;
  const int xi = pix & 31, yi = pix >> 5;
  const float hw = c_aw[a]*0.5f, hh = c_ah[a]*0.5f;
  const float xc = xi + 0.5f, yc = yi + 0.5f;
  Anc A;
  A.x1 = fminf(fmaxf(xc - hw, 0.f), 32.f);
  A.y1 = fminf(fmaxf(yc - hh, 0.f), 32.f);
  A.x2 = fminf(fmaxf(xc + hw, 0.f), 32.f);
  A.y2 = fminf(fmaxf(yc + hh, 0.f), 32.f);
  A.areaA = __fmul_rn(__fsub_rn(A.x2, A.x1), __fsub_rn(A.y2, A.y1));
  return A;
}
__device__ __forceinline__ float iou_one(const Anc& A, float4 gp) {
  const float gx1 = gp.x * 0.03125f, gy1 = gp.y * 0.03125f;   // /32 exact
  const float gx2 = gp.z * 0.03125f, gy2 = gp.w * 0.03125f;
  const float dx = fmaxf(__fsub_rn(fminf(A.x2, gx2), fmaxf(A.x1, gx1)), 0.f);
  const float dy = fmaxf(__fsub_rn(fminf(A.y2, gy2), fmaxf(A.y1, gy1)), 0.f);
  const float inter = __fmul_rn(dx, dy);
  const float areaG = __fmul_rn(__fsub_rn(gx2, gx1), __fsub_rn(gy2, gy1));
  const float den = __fadd_rn(__fsub_rn(__fadd_rn(A.areaA, areaG), inter), 1e-8f);
  return __fdiv_rn(inter, den);
}

__device__ __forceinline__ float softplusf(float z) {
  return fmaxf(z, 0.f) + log1pf(expf(-fabsf(z)));
}
__device__ __forceinline__ float sl1f(float d) {
  const float ad = fabsf(d);
  return ad < 1.f ? 0.5f*d*d : ad - 0.5f;
}

union SMem {
  struct { unsigned short As[128*64]; unsigned short Bs[128*64]; } conv;  // 32 KB
  struct { float tile[64][33]; } tx;
  struct { unsigned short wlds[9*1024]; } wt;
  struct { float red[4]; } mx;
  struct { float red[4][16][48]; float hl[16][49]; float4 gt[20]; float mg[20]; } p2;
};

__global__ __launch_bounds__(256, 4)
void k_rpn(const float* __restrict__ x,   const float* __restrict__ gtb,
           const float* __restrict__ w1,  const float* __restrict__ b1,
           const float* __restrict__ cw,  const float* __restrict__ cb,
           const float* __restrict__ rw,  const float* __restrict__ rb,
           unsigned short* __restrict__ xh, unsigned short* __restrict__ wt,
           unsigned short* __restrict__ wh, float* __restrict__ hb,
           unsigned int* __restrict__ maxg, float* __restrict__ sums,
           unsigned int* __restrict__ ctr,  unsigned short* __restrict__ hidp,
           unsigned int* __restrict__ bar,  float* __restrict__ out) {
  __shared__ SMem sm;
  const int bid = blockIdx.x;
  const int t = threadIdx.x;

  // ================= P0: prep =================
  // ---- 4 x-transpose units per block: NCHW f32 -> halo NHWC bf16
  for (int j = 0; j < 4; ++j) {
    const int u = bid*4 + j;
    const int c0 = (u & 31) << 6;
    const int h  = (u >> 5) & 31;
    const int b  = u >> 10;
    const int w = t & 31, cl = t >> 5;
    const float* src = x + (((size_t)b*NC + c0)*NH + h)*NW;
    float v[8];
#pragma unroll
    for (int k = 0; k < 8; ++k)
      v[k] = src[(size_t)(cl + k*8)*NH*NW + w];
    __syncthreads();                       // protect previous iteration's tile reads
#pragma unroll
    for (int k = 0; k < 8; ++k)
      sm.tx.tile[cl + k*8][w] = v[k];
    __syncthreads();
    unsigned short* dst = xh + ((size_t)(b*34 + h + 1)*34 + 1)*2048 + c0;
    const int w2 = t >> 3, c8 = (t & 7) << 3;
    unsigned int pk[4];
#pragma unroll
    for (int k = 0; k < 4; ++k) {
      const unsigned int lo = f2bf(sm.tx.tile[c8 + 2*k][w2]);
      const unsigned int hi = f2bf(sm.tx.tile[c8 + 2*k + 1][w2]);
      pk[k] = lo | (hi << 16);
    }
    *(uint4*)(dst + (size_t)w2*2048 + c8) = make_uint4(pk[0], pk[1], pk[2], pk[3]);
  }
  __syncthreads();

  // ---- 1 w-transpose unit per block: w1 -> [g][O][C] bf16, LDS-staged
  {
    const int o = bid >> 1, half = bid & 1;
    const int c_base = half << 10;
    const float* src = w1 + ((size_t)(o*2048 + c_base))*9;
#pragma unroll
    for (int j = 0; j < 9; ++j) {
      const int f0 = (j*256 + t)*4;
      const float4 v = *(const float4*)(src + f0);
      const float vv[4] = {v.x, v.y, v.z, v.w};
#pragma unroll
      for (int e = 0; e < 4; ++e) {
        const int f = f0 + e;
        const int c = f/9, g = f - c*9;
        sm.wt.wlds[g*1024 + c] = f2bf(vv[e]);
      }
    }
    __syncthreads();
#pragma unroll
    for (int j = 0; j < 5; ++j) {
      const int idx = j*256 + t;
      if (idx < 1152) {
        const int g = idx >> 7, off = (idx & 127) << 3;
        *(uint4*)(wt + (size_t)g*NHID*NC + o*2048 + c_base + off) =
            *(const uint4*)(sm.wt.wlds + g*1024 + off);
      }
    }
  }
  __syncthreads();

  // ---- extras by bid
  if (bid < 96) {                          // head weights [48][512] + bias
    const int q = bid*256 + t;
    const int n = q >> 9, c = q & 511;
    float v = 0.f;
    if (n < 9) v = cw[n*512 + c];
    else if (n < 45) v = rw[(n-9)*512 + c];
    wh[q] = f2bf(v);
    if (c == 0) {
      float bv = 0.f;
      if (n < 9) bv = cb[n];
      else if (n < 45) bv = rb[n-9];
      hb[n] = bv;
    }
  }
  if (bid < 528) {                         // zero one halo cell (2048 bf16)
    const int b = bid / 132, hc = bid - b*132;
    int hh, ww;
    if (hc < 34)       { hh = 0;        ww = hc; }
    else if (hc < 68)  { hh = 33;       ww = hc - 34; }
    else if (hc < 100) { hh = hc - 67;  ww = 0; }
    else               { hh = hc - 99;  ww = 33; }
    uint4* dst = (uint4*)(xh + ((size_t)((b*34 + hh)*34 + ww))*2048);
    dst[t] = make_uint4(0u, 0u, 0u, 0u);
  } else if (bid < 608) {                  // per-GT max IoU for one (b,g)
    const int p = bid - 528;
    const int b = p / NG, g = p - b*NG;
    const float4 gp = *(const float4*)(gtb + ((size_t)b*NG + g)*4);
    float m = 0.f;
#pragma unroll
    for (int j = 0; j < 36; ++j)
      m = fmaxf(m, iou_one(anc_of(t + j*256), gp));
#pragma unroll
    for (int o = 32; o > 0; o >>= 1) m = fmaxf(m, __shfl_xor(m, o));
    if ((t & 63) == 0) sm.mx.red[t >> 6] = m;
    __syncthreads();
    if (t == 0)
      maxg[b*NG + g] = __float_as_uint(
          fmaxf(fmaxf(sm.mx.red[0], sm.mx.red[1]), fmaxf(sm.mx.red[2], sm.mx.red[3])));
  } else if (bid == 608) {                 // flags
    if (t < 2) sums[t] = 0.f;
    else if (t == 2) *ctr = 0u;
  }

  gbar(bar + 0);

  // ================= P1: conv 3x3 as implicit GEMM (16x16x32, R6-verified) =================
  {
    const int kz = bid & 7;                // XCD swizzle: c-slice per XCD (L2-resident)
    const int rem = bid >> 3;
    const int tileM = rem & 31, tileN = rem >> 5;
    const int b = tileM >> 3, h0 = (tileM & 7) << 2;
    const int o0 = tileN << 7;
    const int wv = t >> 6, lane = t & 63;
    const int wm = wv >> 1, wn = wv & 1;
    const int quad = lane >> 4, l16 = lane & 15;
    const int c_base = kz * CSPLIT;

    floatx4 acc[4][4];
#pragma unroll
    for (int mt = 0; mt < 4; ++mt)
#pragma unroll
      for (int nt = 0; nt < 4; ++nt)
        acc[mt][nt] = (floatx4){0.f, 0.f, 0.f, 0.f};

    const int lr = lane >> 3, pos = lane & 7;
    int gA[4], gB[4];
#pragma unroll
    for (int j = 0; j < 4; ++j) {
      const int row = wv*32 + j*8 + lr;
      const int sd = (pos - row) & 7;      // seg swizzle (measured: 0 conflicts)
      const int hh = h0 + (row >> 5) + 1, ww = (row & 31) + 1;
      gA[j] = ((b*34 + hh)*34 + ww)*2048 + c_base + sd*8;
      gB[j] = (o0 + row)*2048 + c_base + sd*8;
    }

    for (int g = 0; g < 9; ++g) {
      const int dsp = ((g/3 - 1)*34 + (g%3 - 1)) * 2048;
      const unsigned short* wgp = wt + (size_t)g*NHID*NC;
      for (int c0 = 0; c0 < CSPLIT; c0 += 64) {
#pragma unroll
        for (int j = 0; j < 4; ++j) {
          gload16(xh + gA[j] + dsp + c0, sm.conv.As + (wv*32 + j*8)*64);
          gload16(wgp + gB[j] + c0,      sm.conv.Bs + (wv*32 + j*8)*64);
        }
        __syncthreads();
#pragma unroll
        for (int sub = 0; sub < 2; ++sub) {
          const int ps = ((sub*4 + quad) + l16) & 7;
          bf16x8 af[4], bw[4];
#pragma unroll
          for (int mt = 0; mt < 4; ++mt)
            af[mt] = *(const bf16x8*)(sm.conv.As + (wm*64 + mt*16 + l16)*64 + ps*8);
#pragma unroll
          for (int nt = 0; nt < 4; ++nt)
            bw[nt] = *(const bf16x8*)(sm.conv.Bs + (wn*64 + nt*16 + l16)*64 + ps*8);
#pragma unroll
          for (int mt = 0; mt < 4; ++mt)
#pragma unroll
            for (int nt = 0; nt < 4; ++nt)
              acc[mt][nt] = __builtin_amdgcn_mfma_f32_16x16x32_bf16(af[mt], bw[nt], acc[mt][nt], 0, 0, 0);
        }
        __syncthreads();
      }
    }
    unsigned short* hp = hidp + (size_t)kz*NM*NHID;
#pragma unroll
    for (int mt = 0; mt < 4; ++mt) {
      const int m = tileM*128 + wm*64 + mt*16 + quad*4;   // D: row = quad*4+reg
#pragma unroll
      for (int nt = 0; nt < 4; ++nt) {
        const int o = o0 + wn*64 + nt*16 + l16;           // D: col = lane&15
#pragma unroll
        for (int r = 0; r < 4; ++r)
          hp[(size_t)(m + r)*NHID + o] = f2bf(acc[mt][nt][r]);
      }
    }
  }

  gbar(bar + 16);

  // ================= P2: heads GEMM + assignment (blocks 0..255) =================
  if (bid >= 256) return;
  {
    const int b = bid >> 6, pix0 = (bid & 63) << 4;
    if (t < 20) {
      sm.p2.gt[t] = *(const float4*)(gtb + ((size_t)b*NG + t)*4);
      sm.p2.mg[t] = __uint_as_float(maxg[b*NG + t]);
    }

    const int wv = t >> 6, lane = t & 63;
    const int quad = lane >> 4, l16 = lane & 15;
    floatx4 acc[3];
#pragma unroll
    for (int nt = 0; nt < 3; ++nt) acc[nt] = (floatx4){0.f, 0.f, 0.f, 0.f};

    const int m = bid*16 + l16;
#pragma unroll
    for (int kk = 0; kk < 4; ++kk) {
      const int ch0 = wv*128 + kk*32 + quad*8;
      float s[8] = {0.f,0.f,0.f,0.f,0.f,0.f,0.f,0.f};
      const size_t gi = (size_t)m*NHID + ch0;
      for (int sp = 0; sp < NSPLIT; ++sp) {
        const uint4 v = *(const uint4*)(hidp + (size_t)sp*NM*NHID + gi);
        s[0] += __uint_as_float(v.x << 16); s[1] += __uint_as_float(v.x & 0xffff0000u);
        s[2] += __uint_as_float(v.y << 16); s[3] += __uint_as_float(v.y & 0xffff0000u);
        s[4] += __uint_as_float(v.z << 16); s[5] += __uint_as_float(v.z & 0xffff0000u);
        s[6] += __uint_as_float(v.w << 16); s[7] += __uint_as_float(v.w & 0xffff0000u);
      }
      union { unsigned short u[8]; bf16x8 v; } af;
#pragma unroll
      for (int e = 0; e < 8; ++e)
        af.u[e] = f2bf(fmaxf(s[e] + b1[ch0 + e], 0.f));
#pragma unroll
      for (int nt = 0; nt < 3; ++nt) {
        const bf16x8 bf = *(const bf16x8*)(wh + (size_t)(nt*16 + l16)*NHID + ch0);
        acc[nt] = __builtin_amdgcn_mfma_f32_16x16x32_bf16(af.v, bf, acc[nt], 0, 0, 0);
      }
    }
#pragma unroll
    for (int nt = 0; nt < 3; ++nt)
#pragma unroll
      for (int r = 0; r < 4; ++r)
        sm.p2.red[wv][quad*4 + r][nt*16 + l16] = acc[nt][r];
    __syncthreads();
#pragma unroll
    for (int j = 0; j < 3; ++j) {
      const int idx = t + j*256;
      const int i = idx / 48, c = idx - i*48;
      sm.p2.hl[i][c] = sm.p2.red[0][i][c] + sm.p2.red[1][i][c]
                     + sm.p2.red[2][i][c] + sm.p2.red[3][i][c] + hb[c];
    }
    __syncthreads();

    float cs = 0.f, rs = 0.f;
    if (t < 144) {
      const int pixL = t / 9, a = t - pixL*9;
      const int pix = pix0 + pixL;
      const int n = pix*9 + a;
      const int idx = b*NANC + n;
      const Anc A = anc_of(n);

      float mx = -1.f; int gi = 0; bool pos = false;
      for (int g = 0; g < NG; ++g) {
        const float v = iou_one(A, sm.p2.gt[g]);    // bit-identical to P0 maxg
        const float mg = sm.p2.mg[g];
        pos = pos || (v > 0.7f) || ((v == mg) && (mg > 1e-8f));
        if (v > mx) { mx = v; gi = g; }
      }
      const bool neg = (mx < 0.3f) && !pos;
      const float posf = pos ? 1.f : 0.f;

      const float conf = sm.p2.hl[pixL][a];
      const float of0 = sm.p2.hl[pixL][9 + a*4 + 0];
      const float of1 = sm.p2.hl[pixL][9 + a*4 + 1];
      const float of2 = sm.p2.hl[pixL][9 + a*4 + 2];
      const float of3 = sm.p2.hl[pixL][9 + a*4 + 3];

      if (pos) cs = softplusf(-conf);
      else if (neg) cs = softplusf(conf);

      const float acx = (A.x1 + A.x2)*0.5f, acy = (A.y1 + A.y2)*0.5f;
      const float aw = A.x2 - A.x1, ah = A.y2 - A.y1;
      if (pos) {
        const float4 gp = sm.p2.gt[gi];
        const float gx1 = gp.x*0.03125f, gy1 = gp.y*0.03125f;
        const float gx2 = gp.z*0.03125f, gy2 = gp.w*0.03125f;
        const float gcx = (gx1+gx2)*0.5f, gcy = (gy1+gy2)*0.5f;
        const float gw = gx2-gx1, gh = gy2-gy1;
        const float t0 = (gcx-acx)/(aw+1e-8f), t1 = (gcy-acy)/(ah+1e-8f);
        const float t2 = logf((gw+1e-8f)/(aw+1e-8f)), t3 = logf((gh+1e-8f)/(ah+1e-8f));
        rs = sl1f(of0-t0) + sl1f(of1-t1) + sl1f(of2-t2) + sl1f(of3-t3);
      }

      const float pcx = acx + of0*aw, pcy = acy + of1*ah;
      const float pw = aw*expf(of2), ph = ah*expf(of3);
      float* op = out + 1 + (size_t)idx*4;
      op[0] = (pcx - pw*0.5f)*posf;
      op[1] = (pcy - ph*0.5f)*posf;
      op[2] = (pcx + pw*0.5f)*posf;
      op[3] = (pcy + ph*0.5f)*posf;
      out[1 + 4*(size_t)NB*NANC + idx] = posf;
    }
#pragma unroll
    for (int o = 32; o > 0; o >>= 1) { cs += __shfl_xor(cs, o); rs += __shfl_xor(rs, o); }
    if ((t & 63) == 0) { atomicAdd(&sums[0], cs); atomicAdd(&sums[1], rs); }

    __syncthreads();
    if (t == 0) {
      __threadfence();
      const unsigned int c = atomicAdd(ctr, 1u);
      if (c == 255u) {
        __threadfence();
        const float fcs = atomicAdd(&sums[0], 0.f);
        const float frs = atomicAdd(&sums[1], 0.f);
        out[0] = fcs*0.25f + 5.f*(frs*0.25f);   // w_conf*cls/B + w_reg*reg/B
      }
    }
  }
}

extern "C" void kernel_launch(void* const* d_in, const int* in_sizes, int n_in,
                              void* d_out, int out_size, void* d_ws, size_t ws_size,
                              hipStream_t stream) {
  const float* x   = (const float*)d_in[0];
  const float* gtb = (const float*)d_in[1];
  // d_in[2] = gt_classes (unused by the loss)
  const float* w1  = (const float*)d_in[3];
  const float* b1  = (const float*)d_in[4];
  const float* cw  = (const float*)d_in[5];
  const float* cb  = (const float*)d_in[6];
  const float* rw  = (const float*)d_in[7];
  const float* rb  = (const float*)d_in[8];
  float* out = (float*)d_out;
  char* ws = (char*)d_ws;

  unsigned short* xh   = (unsigned short*)(ws + OFF_XH);
  unsigned short* wt   = (unsigned short*)(ws + OFF_WT);
  unsigned short* wh   = (unsigned short*)(ws + OFF_WH);
  float*          hb   = (float*)(ws + OFF_HB);
  unsigned int*   maxg = (unsigned int*)(ws + OFF_MAXG);
  float*          sums = (float*)(ws + OFF_SUMS);
  unsigned int*   ctr  = (unsigned int*)(ws + OFF_CTR);
  unsigned short* hidp = (unsigned short*)(ws + OFF_HIDP);
  unsigned int*   bar  = (unsigned int*)(ws + OFF_BAR);

  k_rpn<<<1024, 256, 0, stream>>>(x, gtb, w1, b1, cw, cb, rw, rb,
                                  xh, wt, wh, hb, maxg, sums, ctr, hidp, bar, out);
}

// Round 10
// 521.539 us; speedup vs baseline: 1.0520x; 1.0520x over previous
//
#include <hip/hip_runtime.h>

// RPN forward on gfx950. R9: same ONE-kernel fused structure as R8 (verified correct,
// absmax 28.125) with the grid-barrier spin fixed: poll via relaxed agent-scope atomic
// LOAD (concurrent, no ownership) instead of atomicAdd RMW (serialized at the cross-XCD
// coherence point -> R8's 2x175us barrier stalls, MfmaUtil 6.6%).
// Phases: P0 prep -> bar -> P1 conv (16x16x32, LDS-bound ~72us) -> bar -> P2 heads+assign.

typedef __bf16 bf16x8 __attribute__((ext_vector_type(8)));
typedef float floatx4 __attribute__((ext_vector_type(4)));

#define NB 4
#define NC 2048
#define NH 32
#define NW 32
#define NHID 512
#define NA 9
#define NG 20
#define NANC 9216
#define NM 4096
#define NSPLIT 8
#define CSPLIT 256            // NC / NSPLIT

// workspace layout (bytes)
#define OFF_XH    0ull            // [4][34][34][2048] bf16 (zero halo) = 18939904
#define OFF_WT    18939904ull     // [9][512][2048]    bf16 = 18874368
#define OFF_WH    37814272ull     // [48][512]         bf16
#define OFF_HB    37863424ull     // [48] f32 (pad 256)
#define OFF_MAXG  37863680ull     // [4][20] uint (pad 512)
#define OFF_SUMS  37864192ull     // [2] f32 (pad 128)
#define OFF_CTR   37864320ull     // [1] uint (pad 128)
#define OFF_HIDP  37864448ull     // [8][4096][512] bf16 = 33554432
#define OFF_BAR   71418880ull     // spin-barrier counters (poison-based), 64B apart

#define POISON 0xAAAAAAAAu

__device__ __forceinline__ unsigned short f2bf(float f) {
  unsigned int u = __float_as_uint(f);
  u = (u + 0x7fffu + ((u >> 16) & 1u)) >> 16;   // RNE
  return (unsigned short)u;
}

__device__ __forceinline__ void gload16(const void* g, void* l) {
  __builtin_amdgcn_global_load_lds(
      (const __attribute__((address_space(1))) unsigned int*)g,
      (__attribute__((address_space(3))) unsigned int*)l, 16, 0, 0);
}

// grid-wide barrier: all 1024 blocks co-resident (4/CU: 256 thr, 64 VGPR, 32KB LDS).
// Counter starts at ws-poison 0xAAAAAAAA; wrap-safe compare; bounded spin (no hang).
// Arrival = one RMW/block; polling = relaxed agent-scope LOADs (concurrent, cheap).
__device__ __forceinline__ void gbar(unsigned int* bar) {
  __syncthreads();
  if (threadIdx.x == 0) {
    __threadfence();                       // release: L2 writeback (agent scope)
    atomicAdd(bar, 1u);
    int spins = 0;
    while ((__hip_atomic_load(bar, __ATOMIC_RELAXED, __HIP_MEMORY_SCOPE_AGENT) - POISON) < 1024u) {
      __builtin_amdgcn_s_sleep(64);        // ~4K cycles between polls
      if (++spins > 1000000) break;        // fail visibly, never hang
    }
    __threadfence();                       // acquire: cache invalidate
  }
  __syncthreads();
}

__constant__ float c_aw[9] = {2.f,2.f,2.f,4.f,4.f,4.f,6.f,6.f,6.f};
__constant__ float c_ah[9] = {1.f,2.f,3.f,2.f,4.f,6.f,3.f,6.f,9.f};

// ---- strict-f32 anchor/IoU helpers (bit-identical across phases) ----
struct Anc { float x1, y1, x2, y2, areaA; };
__device__ __forceinline__ Anc anc_of(int n) {
  const int a = n % 9, pix = n / 9;
  const int xi = pix & 31, yi = pix >> 5;
  const float hw = c_aw[a]*0.5f, hh = c_ah[a]*0.5f;
  const float xc = xi + 0.5f, yc = yi + 0.5f;
  Anc A;
  A.x1 = fminf(fmaxf(xc - hw, 0.f), 32.f);
  A.y1 = fminf(fmaxf(yc - hh, 0.f), 32.f);
  A.x2 = fminf(fmaxf(xc + hw, 0.f), 32.f);
  A.y2 = fminf(fmaxf(yc + hh, 0.f), 32.f);
  A.areaA = __fmul_rn(__fsub_rn(A.x2, A.x1), __fsub_rn(A.y2, A.y1));
  return A;
}
__device__ __forceinline__ float iou_one(const Anc& A, float4 gp) {
  const float gx1 = gp.x * 0.03125f, gy1 = gp.y * 0.03125f;   // /32 exact
  const float gx2 = gp.z * 0.03125f, gy2 = gp.w * 0.03125f;
  const float dx = fmaxf(__fsub_rn(fminf(A.x2, gx2), fmaxf(A.x1, gx1)), 0.f);
  const float dy = fmaxf(__fsub_rn(fminf(A.y2, gy2), fmaxf(A.y1, gy1)), 0.f);
  const float inter = __fmul_rn(dx, dy);
  const float areaG = __fmul_rn(__fsub_rn(gx2, gx1), __fsub_rn(gy2, gy1));
  const float den = __fadd_rn(__fsub_rn(__fadd_rn(A.areaA, areaG), inter), 1e-8f);
  return __fdiv_rn(inter, den);
}

__device__ __forceinline__ float softplusf(float z) {
  return fmaxf(z, 0.f) + log1pf(expf(-fabsf(z)));
}
__device__ __forceinline__ float sl1f(float d) {
  const float ad = fabsf(d);
  return ad < 1.f ? 0.5f*d*d : ad - 0.5f;
}

union SMem {
  struct { unsigned short As[128*64]; unsigned short Bs[128*64]; } conv;  // 32 KB
  struct { float tile[64][33]; } tx;
  struct { unsigned short wlds[9*1024]; } wt;
  struct { float red[4]; } mx;
  struct { float red[4][16][48]; float hl[16][49]; float4 gt[20]; float mg[20]; } p2;
};

__global__ __launch_bounds__(256, 4)
void k_rpn(const float* __restrict__ x,   const float* __restrict__ gtb,
           const float* __restrict__ w1,  const float* __restrict__ b1,
           const float* __restrict__ cw,  const float* __restrict__ cb,
           const float* __restrict__ rw,  const float* __restrict__ rb,
           unsigned short* __restrict__ xh, unsigned short* __restrict__ wt,
           unsigned short* __restrict__ wh, float* __restrict__ hb,
           unsigned int* __restrict__ maxg, float* __restrict__ sums,
           unsigned int* __restrict__ ctr,  unsigned short* __restrict__ hidp,
           unsigned int* __restrict__ bar,  float* __restrict__ out) {
  __shared__ SMem sm;
  const int bid = blockIdx.x;
  const int t = threadIdx.x;

  // ================= P0: prep =================
  // ---- 4 x-transpose units per block: NCHW f32 -> halo NHWC bf16
  for (int j = 0; j < 4; ++j) {
    const int u = bid*4 + j;
    const int c0 = (u & 31) << 6;
    const int h  = (u >> 5) & 31;
    const int b  = u >> 10;
    const int w = t & 31, cl = t >> 5;
    const float* src = x + (((size_t)b*NC + c0)*NH + h)*NW;
    float v[8];
#pragma unroll
    for (int k = 0; k < 8; ++k)
      v[k] = src[(size_t)(cl + k*8)*NH*NW + w];
    __syncthreads();                       // protect previous iteration's tile reads
#pragma unroll
    for (int k = 0; k < 8; ++k)
      sm.tx.tile[cl + k*8][w] = v[k];
    __syncthreads();
    unsigned short* dst = xh + ((size_t)(b*34 + h + 1)*34 + 1)*2048 + c0;
    const int w2 = t >> 3, c8 = (t & 7) << 3;
    unsigned int pk[4];
#pragma unroll
    for (int k = 0; k < 4; ++k) {
      const unsigned int lo = f2bf(sm.tx.tile[c8 + 2*k][w2]);
      const unsigned int hi = f2bf(sm.tx.tile[c8 + 2*k + 1][w2]);
      pk[k] = lo | (hi << 16);
    }
    *(uint4*)(dst + (size_t)w2*2048 + c8) = make_uint4(pk[0], pk[1], pk[2], pk[3]);
  }
  __syncthreads();

  // ---- 1 w-transpose unit per block: w1 -> [g][O][C] bf16, LDS-staged
  {
    const int o = bid >> 1, half = bid & 1;
    const int c_base = half << 10;
    const float* src = w1 + ((size_t)(o*2048 + c_base))*9;
#pragma unroll
    for (int j = 0; j < 9; ++j) {
      const int f0 = (j*256 + t)*4;
      const float4 v = *(const float4*)(src + f0);
      const float vv[4] = {v.x, v.y, v.z, v.w};
#pragma unroll
      for (int e = 0; e < 4; ++e) {
        const int f = f0 + e;
        const int c = f/9, g = f - c*9;
        sm.wt.wlds[g*1024 + c] = f2bf(vv[e]);
      }
    }
    __syncthreads();
#pragma unroll
    for (int j = 0; j < 5; ++j) {
      const int idx = j*256 + t;
      if (idx < 1152) {
        const int g = idx >> 7, off = (idx & 127) << 3;
        *(uint4*)(wt + (size_t)g*NHID*NC + o*2048 + c_base + off) =
            *(const uint4*)(sm.wt.wlds + g*1024 + off);
      }
    }
  }
  __syncthreads();

  // ---- extras by bid
  if (bid < 96) {                          // head weights [48][512] + bias
    const int q = bid*256 + t;
    const int n = q >> 9, c = q & 511;
    float v = 0.f;
    if (n < 9) v = cw[n*512 + c];
    else if (n < 45) v = rw[(n-9)*512 + c];
    wh[q] = f2bf(v);
    if (c == 0) {
      float bv = 0.f;
      if (n < 9) bv = cb[n];
      else if (n < 45) bv = rb[n-9];
      hb[n] = bv;
    }
  }
  if (bid < 528) {                         // zero one halo cell (2048 bf16)
    const int b = bid / 132, hc = bid - b*132;
    int hh, ww;
    if (hc < 34)       { hh = 0;        ww = hc; }
    else if (hc < 68)  { hh = 33;       ww = hc - 34; }
    else if (hc < 100) { hh = hc - 67;  ww = 0; }
    else               { hh = hc - 99;  ww = 33; }
    uint4* dst = (uint4*)(xh + ((size_t)((b*34 + hh)*34 + ww))*2048);
    dst[t] = make_uint4(0u, 0u, 0u, 0u);
  } else if (bid < 608) {                  // per-GT max IoU for one (b,g)
    const int p = bid - 528;
    const int b = p / NG, g = p - b*NG;
    const float4 gp = *(const float4*)(gtb + ((size_t)b*NG + g)*4);
    float m = 0.f;
#pragma unroll
    for (int j = 0; j < 36; ++j)
      m = fmaxf(m, iou_one(anc_of(t + j*256), gp));
#pragma unroll
    for (int o = 32; o > 0; o >>= 1) m = fmaxf(m, __shfl_xor(m, o));
    if ((t & 63) == 0) sm.mx.red[t >> 6] = m;
    __syncthreads();
    if (t == 0)
      maxg[b*NG + g] = __float_as_uint(
          fmaxf(fmaxf(sm.mx.red[0], sm.mx.red[1]), fmaxf(sm.mx.red[2], sm.mx.red[3])));
  } else if (bid == 608) {                 // flags
    if (t < 2) sums[t] = 0.f;
    else if (t == 2) *ctr = 0u;
  }

  gbar(bar + 0);

  // ================= P1: conv 3x3 as implicit GEMM (16x16x32) =================
  {
    const int kz = bid & 7;                // XCD swizzle: c-slice per XCD (L2-resident)
    const int rem = bid >> 3;
    const int tileM = rem & 31, tileN = rem >> 5;
    const int b = tileM >> 3, h0 = (tileM & 7) << 2;
    const int o0 = tileN << 7;
    const int wv = t >> 6, lane = t & 63;
    const int wm = wv >> 1, wn = wv & 1;
    const int quad = lane >> 4, l16 = lane & 15;
    const int c_base = kz * CSPLIT;

    floatx4 acc[4][4];
#pragma unroll
    for (int mt = 0; mt < 4; ++mt)
#pragma unroll
      for (int nt = 0; nt < 4; ++nt)
        acc[mt][nt] = (floatx4){0.f, 0.f, 0.f, 0.f};

    const int lr = lane >> 3, pos = lane & 7;
    int gA[4], gB[4];
#pragma unroll
    for (int j = 0; j < 4; ++j) {
      const int row = wv*32 + j*8 + lr;
      const int sd = (pos - row) & 7;      // seg swizzle (measured: 0 conflicts)
      const int hh = h0 + (row >> 5) + 1, ww = (row & 31) + 1;
      gA[j] = ((b*34 + hh)*34 + ww)*2048 + c_base + sd*8;
      gB[j] = (o0 + row)*2048 + c_base + sd*8;
    }

    for (int g = 0; g < 9; ++g) {
      const int dsp = ((g/3 - 1)*34 + (g%3 - 1)) * 2048;
      const unsigned short* wgp = wt + (size_t)g*NHID*NC;
      for (int c0 = 0; c0 < CSPLIT; c0 += 64) {
#pragma unroll
        for (int j = 0; j < 4; ++j) {
          gload16(xh + gA[j] + dsp + c0, sm.conv.As + (wv*32 + j*8)*64);
          gload16(wgp + gB[j] + c0,      sm.conv.Bs + (wv*32 + j*8)*64);
        }
        __syncthreads();
#pragma unroll
        for (int sub = 0; sub < 2; ++sub) {
          const int ps = ((sub*4 + quad) + l16) & 7;
          bf16x8 af[4], bw[4];
#pragma unroll
          for (int mt = 0; mt < 4; ++mt)
            af[mt] = *(const bf16x8*)(sm.conv.As + (wm*64 + mt*16 + l16)*64 + ps*8);
#pragma unroll
          for (int nt = 0; nt < 4; ++nt)
            bw[nt] = *(const bf16x8*)(sm.conv.Bs + (wn*64 + nt*16 + l16)*64 + ps*8);
#pragma unroll
          for (int mt = 0; mt < 4; ++mt)
#pragma unroll
            for (int nt = 0; nt < 4; ++nt)
              acc[mt][nt] = __builtin_amdgcn_mfma_f32_16x16x32_bf16(af[mt], bw[nt], acc[mt][nt], 0, 0, 0);
        }
        __syncthreads();
      }
    }
    unsigned short* hp = hidp + (size_t)kz*NM*NHID;
#pragma unroll
    for (int mt = 0; mt < 4; ++mt) {
      const int m = tileM*128 + wm*64 + mt*16 + quad*4;   // D: row = quad*4+reg
#pragma unroll
      for (int nt = 0; nt < 4; ++nt) {
        const int o = o0 + wn*64 + nt*16 + l16;           // D: col = lane&15
#pragma unroll
        for (int r = 0; r < 4; ++r)
          hp[(size_t)(m + r)*NHID + o] = f2bf(acc[mt][nt][r]);
      }
    }
  }

  gbar(bar + 16);

  // ================= P2: heads GEMM + assignment (blocks 0..255) =================
  if (bid >= 256) return;
  {
    const int b = bid >> 6, pix0 = (bid & 63) << 4;
    if (t < 20) {
      sm.p2.gt[t] = *(const float4*)(gtb + ((size_t)b*NG + t)*4);
      sm.p2.mg[t] = __uint_as_float(maxg[b*NG + t]);
    }

    const int wv = t >> 6, lane = t & 63;
    const int quad = lane >> 4, l16 = lane & 15;
    floatx4 acc[3];
#pragma unroll
    for (int nt = 0; nt < 3; ++nt) acc[nt] = (floatx4){0.f, 0.f, 0.f, 0.f};

    const int m = bid*16 + l16;
#pragma unroll
    for (int kk = 0; kk < 4; ++kk) {
      const int ch0 = wv*128 + kk*32 + quad*8;
      float s[8] = {0.f,0.f,0.f,0.f,0.f,0.f,0.f,0.f};
      const size_t gi = (size_t)m*NHID + ch0;
      for (int sp = 0; sp < NSPLIT; ++sp) {
        const uint4 v = *(const uint4*)(hidp + (size_t)sp*NM*NHID + gi);
        s[0] += __uint_as_float(v.x << 16); s[1] += __uint_as_float(v.x & 0xffff0000u);
        s[2] += __uint_as_float(v.y << 16); s[3] += __uint_as_float(v.y & 0xffff0000u);
        s[4] += __uint_as_float(v.z << 16); s[5] += __uint_as_float(v.z & 0xffff0000u);
        s[6] += __uint_as_float(v.w << 16); s[7] += __uint_as_float(v.w & 0xffff0000u);
      }
      union { unsigned short u[8]; bf16x8 v; } af;
#pragma unroll
      for (int e = 0; e < 8; ++e)
        af.u[e] = f2bf(fmaxf(s[e] + b1[ch0 + e], 0.f));
#pragma unroll
      for (int nt = 0; nt < 3; ++nt) {
        const bf16x8 bf = *(const bf16x8*)(wh + (size_t)(nt*16 + l16)*NHID + ch0);
        acc[nt] = __builtin_amdgcn_mfma_f32_16x16x32_bf16(af.v, bf, acc[nt], 0, 0, 0);
      }
    }
#pragma unroll
    for (int nt = 0; nt < 3; ++nt)
#pragma unroll
      for (int r = 0; r < 4; ++r)
        sm.p2.red[wv][quad*4 + r][nt*16 + l16] = acc[nt][r];
    __syncthreads();
#pragma unroll
    for (int j = 0; j < 3; ++j) {
      const int idx = t + j*256;
      const int i = idx / 48, c = idx - i*48;
      sm.p2.hl[i][c] = sm.p2.red[0][i][c] + sm.p2.red[1][i][c]
                     + sm.p2.red[2][i][c] + sm.p2.red[3][i][c] + hb[c];
    }
    __syncthreads();

    float cs = 0.f, rs = 0.f;
    if (t < 144) {
      const int pixL = t / 9, a = t - pixL*9;
      const int pix = pix0 + pixL;
      const int n = pix*9 + a;
      const int idx = b*NANC + n;
      const Anc A = anc_of(n);

      float mx = -1.f; int gi = 0; bool pos = false;
      for (int g = 0; g < NG; ++g) {
        const float v = iou_one(A, sm.p2.gt[g]);    // bit-identical to P0 maxg
        const float mg = sm.p2.mg[g];
        pos = pos || (v > 0.7f) || ((v == mg) && (mg > 1e-8f));
        if (v > mx) { mx = v; gi = g; }
      }
      const bool neg = (mx < 0.3f) && !pos;
      const float posf = pos ? 1.f : 0.f;

      const float conf = sm.p2.hl[pixL][a];
      const float of0 = sm.p2.hl[pixL][9 + a*4 + 0];
      const float of1 = sm.p2.hl[pixL][9 + a*4 + 1];
      const float of2 = sm.p2.hl[pixL][9 + a*4 + 2];
      const float of3 = sm.p2.hl[pixL][9 + a*4 + 3];

      if (pos) cs = softplusf(-conf);
      else if (neg) cs = softplusf(conf);

      const float acx = (A.x1 + A.x2)*0.5f, acy = (A.y1 + A.y2)*0.5f;
      const float aw = A.x2 - A.x1, ah = A.y2 - A.y1;
      if (pos) {
        const float4 gp = sm.p2.gt[gi];
        const float gx1 = gp.x*0.03125f, gy1 = gp.y*0.03125f;
        const float gx2 = gp.z*0.03125f, gy2 = gp.w*0.03125f;
        const float gcx = (gx1+gx2)*0.5f, gcy = (gy1+gy2)*0.5f;
        const float gw = gx2-gx1, gh = gy2-gy1;
        const float t0 = (gcx-acx)/(aw+1e-8f), t1 = (gcy-acy)/(ah+1e-8f);
        const float t2 = logf((gw+1e-8f)/(aw+1e-8f)), t3 = logf((gh+1e-8f)/(ah+1e-8f));
        rs = sl1f(of0-t0) + sl1f(of1-t1) + sl1f(of2-t2) + sl1f(of3-t3);
      }

      const float pcx = acx + of0*aw, pcy = acy + of1*ah;
      const float pw = aw*expf(of2), ph = ah*expf(of3);
      float* op = out + 1 + (size_t)idx*4;
      op[0] = (pcx - pw*0.5f)*posf;
      op[1] = (pcy - ph*0.5f)*posf;
      op[2] = (pcx + pw*0.5f)*posf;
      op[3] = (pcy + ph*0.5f)*posf;
      out[1 + 4*(size_t)NB*NANC + idx] = posf;
    }
#pragma unroll
    for (int o = 32; o > 0; o >>= 1) { cs += __shfl_xor(cs, o); rs += __shfl_xor(rs, o); }
    if ((t & 63) == 0) { atomicAdd(&sums[0], cs); atomicAdd(&sums[1], rs); }

    __syncthreads();
    if (t == 0) {
      __threadfence();
      const unsigned int c = atomicAdd(ctr, 1u);
      if (c == 255u) {
        __threadfence();
        const float fcs = atomicAdd(&sums[0], 0.f);
        const float frs = atomicAdd(&sums[1], 0.f);
        out[0] = fcs*0.25f + 5.f*(frs*0.25f);   // w_conf*cls/B + w_reg*reg/B
      }
    }
  }
}

extern "C" void kernel_launch(void* const* d_in, const int* in_sizes, int n_in,
                              void* d_out, int out_size, void* d_ws, size_t ws_size,
                              hipStream_t stream) {
  const float* x   = (const float*)d_in[0];
  const float* gtb = (const float*)d_in[1];
  // d_in[2] = gt_classes (unused by the loss)
  const float* w1  = (const float*)d_in[3];
  const float* b1  = (const float*)d_in[4];
  const float* cw  = (const float*)d_in[5];
  const float* cb  = (const float*)d_in[6];
  const float* rw  = (const float*)d_in[7];
  const float* rb  = (const float*)d_in[8];
  float* out = (float*)d_out;
  char* ws = (char*)d_ws;

  unsigned short* xh   = (unsigned short*)(ws + OFF_XH);
  unsigned short* wt   = (unsigned short*)(ws + OFF_WT);
  unsigned short* wh   = (unsigned short*)(ws + OFF_WH);
  float*          hb   = (float*)(ws + OFF_HB);
  unsigned int*   maxg = (unsigned int*)(ws + OFF_MAXG);
  float*          sums = (float*)(ws + OFF_SUMS);
  unsigned int*   ctr  = (unsigned int*)(ws + OFF_CTR);
  unsigned short* hidp = (unsigned short*)(ws + OFF_HIDP);
  unsigned int*   bar  = (unsigned int*)(ws + OFF_BAR);

  k_rpn<<<1024, 256, 0, stream>>>(x, gtb, w1, b1, cw, cb, rw, rb,
                                  xh, wt, wh, hb, maxg, sums, ctr, hidp, bar, out);
}

// Round 11
// 224.039 us; speedup vs baseline: 2.4489x; 2.3279x over previous
//
#include <hip/hip_runtime.h>

// RPN forward on gfx950. R10: RESTORE of the measured-best R6 structure (228.7 us).
// Fused single-kernel grid-barrier variants (R8/R9) measured 440-470 us — abandoned.
// 3 nodes: k_prep (transposes + head-w + halo + per-GT maxIoU + flags),
//          k_conv_gemm (implicit GEMM, 16x16x32 bf16 MFMA, global_load_lds(16B),
//                       8-pos seg swizzle = 0 bank conflicts, XCD-swizzled split-K,
//                       ~1.07 PF, LDS-read-bound structural plateau),
//          k_heads_assign (register-fragment heads GEMM + assignment + loss, fused finalize).
// pos/neg assignment in strict IEEE f32 (no contraction) to bit-match numpy ref.

typedef __bf16 bf16x8 __attribute__((ext_vector_type(8)));
typedef float floatx4 __attribute__((ext_vector_type(4)));

#define NB 4
#define NC 2048
#define NH 32
#define NW 32
#define NHID 512
#define NA 9
#define NG 20
#define NANC 9216
#define NM 4096

// workspace layout (bytes)
#define OFF_XH    0ull            // [4][34][34][2048] bf16 (zero halo) = 18939904
#define OFF_WT    18939904ull     // [9][512][2048]    bf16 = 18874368
#define OFF_WH    37814272ull     // [48][512]         bf16
#define OFF_HB    37863424ull     // [48] f32 (pad 256)
#define OFF_MAXG  37863680ull     // [4][20] uint (pad 512)
#define OFF_SUMS  37864192ull     // [2] f32 (pad 128)
#define OFF_CTR   37864320ull     // [1] uint (pad 128)
#define OFF_HIDP  37864448ull     // [nsplit][4096][512] bf16, 4194304 each

// k_prep block ranges
#define PREP_TX   4096
#define PREP_W    1024            // 512 o * 2 halves, LDS-staged
#define PREP_WH   96
#define PREP_HALO 528
#define PREP_MAXG 80
#define PREP_NBLK (PREP_TX + PREP_W + PREP_WH + PREP_HALO + PREP_MAXG + 1)

__device__ __forceinline__ unsigned short f2bf(float f) {
  unsigned int u = __float_as_uint(f);
  u = (u + 0x7fffu + ((u >> 16) & 1u)) >> 16;   // RNE
  return (unsigned short)u;
}

__device__ __forceinline__ void gload16(const void* g, void* l) {
  __builtin_amdgcn_global_load_lds(
      (const __attribute__((address_space(1))) unsigned int*)g,
      (__attribute__((address_space(3))) unsigned int*)l, 16, 0, 0);
}

__constant__ float c_aw[9] = {2.f,2.f,2.f,4.f,4.f,4.f,6.f,6.f,6.f};
__constant__ float c_ah[9] = {1.f,2.f,3.f,2.f,4.f,6.f,3.f,6.f,9.f};

// ---- strict-f32 anchor/IoU helpers (bit-identical in prep-maxg + assign) ----
struct Anc { float x1, y1, x2, y2, areaA; };
__device__ __forceinline__ Anc anc_of(int n) {
  const int a = n % 9, pix = n / 9;
  const int xi = pix & 31, yi = pix >> 5;
  const float hw = c_aw[a]*0.5f, hh = c_ah[a]*0.5f;
  const float xc = xi + 0.5f, yc = yi + 0.5f;
  Anc A;
  A.x1 = fminf(fmaxf(xc - hw, 0.f), 32.f);
  A.y1 = fminf(fmaxf(yc - hh, 0.f), 32.f);
  A.x2 = fminf(fmaxf(xc + hw, 0.f), 32.f);
  A.y2 = fminf(fmaxf(yc + hh, 0.f), 32.f);
  A.areaA = __fmul_rn(__fsub_rn(A.x2, A.x1), __fsub_rn(A.y2, A.y1));
  return A;
}
__device__ __forceinline__ float iou_one(const Anc& A, float4 gp) {
  const float gx1 = gp.x * 0.03125f, gy1 = gp.y * 0.03125f;   // /32 exact
  const float gx2 = gp.z * 0.03125f, gy2 = gp.w * 0.03125f;
  const float dx = fmaxf(__fsub_rn(fminf(A.x2, gx2), fmaxf(A.x1, gx1)), 0.f);
  const float dy = fmaxf(__fsub_rn(fminf(A.y2, gy2), fmaxf(A.y1, gy1)), 0.f);
  const float inter = __fmul_rn(dx, dy);
  const float areaG = __fmul_rn(__fsub_rn(gx2, gx1), __fsub_rn(gy2, gy1));
  const float den = __fadd_rn(__fsub_rn(__fadd_rn(A.areaA, areaG), inter), 1e-8f);
  return __fdiv_rn(inter, den);
}

// ---------------- fused prep ----------------
__global__ __launch_bounds__(256) void k_prep(const float* __restrict__ x,
                                              const float* __restrict__ w1,
                                              const float* __restrict__ cw, const float* __restrict__ cb,
                                              const float* __restrict__ rw, const float* __restrict__ rb,
                                              const float* __restrict__ gtb,
                                              unsigned short* __restrict__ xh,
                                              unsigned short* __restrict__ wt,
                                              unsigned short* __restrict__ wh, float* __restrict__ hb,
                                              unsigned int* __restrict__ maxg,
                                              float* __restrict__ sums, unsigned int* __restrict__ ctr) {
  __shared__ float tile[64][33];
  __shared__ unsigned short wlds[9*1024];
  __shared__ float red[4];
  const int bid = blockIdx.x;
  const int tid = threadIdx.x;

  if (bid < PREP_TX) {                       // ---- x: NCHW f32 -> halo NHWC bf16
    const int c0 = (bid & 31) << 6;
    const int h  = (bid >> 5) & 31;
    const int b  = bid >> 10;
    const int w = tid & 31, cl = tid >> 5;
    const float* src = x + (((size_t)b*NC + c0)*NH + h)*NW;
#pragma unroll
    for (int j = 0; j < 8; ++j) {
      const int c = cl + j*8;
      tile[c][w] = src[(size_t)c*NH*NW + w];
    }
    __syncthreads();
    unsigned short* dst = xh + ((size_t)(b*34 + h + 1)*34 + 1)*2048 + c0;
    const int w2 = tid >> 3, c8 = (tid & 7) << 3;   // 16B store per lane
    unsigned int pk[4];
#pragma unroll
    for (int k = 0; k < 4; ++k) {
      const unsigned int lo = f2bf(tile[c8 + 2*k][w2]);
      const unsigned int hi = f2bf(tile[c8 + 2*k + 1][w2]);
      pk[k] = lo | (hi << 16);
    }
    *(uint4*)(dst + (size_t)w2*2048 + c8) = make_uint4(pk[0], pk[1], pk[2], pk[3]);
    return;
  }
  if (bid < PREP_TX + PREP_W) {              // ---- w1 -> [g][O][C] bf16, LDS-staged
    const int p = bid - PREP_TX;
    const int o = p >> 1, half = p & 1;
    const int c_base = half << 10;
    const float* src = w1 + ((size_t)(o*2048 + c_base))*9;   // 9216 contiguous floats
#pragma unroll
    for (int j = 0; j < 9; ++j) {            // read float4, scatter bf16 into [g][c] LDS
      const int f0 = (j*256 + tid)*4;
      const float4 v = *(const float4*)(src + f0);
      const float vv[4] = {v.x, v.y, v.z, v.w};
#pragma unroll
      for (int e = 0; e < 4; ++e) {
        const int f = f0 + e;
        const int c = f/9, g = f - c*9;
        wlds[g*1024 + c] = f2bf(vv[e]);
      }
    }
    __syncthreads();
#pragma unroll
    for (int j = 0; j < 5; ++j) {            // 1152 uint4 writes (9 g * 128)
      const int idx = j*256 + tid;
      if (idx < 1152) {
        const int g = idx >> 7, off = (idx & 127) << 3;
        *(uint4*)(wt + (size_t)g*NHID*NC + o*2048 + c_base + off) =
            *(const uint4*)(wlds + g*1024 + off);
      }
    }
    return;
  }
  if (bid < PREP_TX + PREP_W + PREP_WH) {    // ---- head weights [48][512] + bias
    const int t = (bid - PREP_TX - PREP_W)*256 + tid;
    const int n = t >> 9, c = t & 511;
    float v = 0.f;
    if (n < 9) v = cw[n*512 + c];
    else if (n < 45) v = rw[(n-9)*512 + c];
    wh[t] = f2bf(v);
    if (c == 0) {
      float bv = 0.f;
      if (n < 9) bv = cb[n];
      else if (n < 45) bv = rb[n-9];
      hb[n] = bv;
    }
    return;
  }
  if (bid < PREP_TX + PREP_W + PREP_WH + PREP_HALO) {  // ---- zero one halo cell
    const int q = bid - (PREP_TX + PREP_W + PREP_WH);
    const int b = q / 132, hc = q - b*132;
    int hh, ww;
    if (hc < 34)       { hh = 0;        ww = hc; }
    else if (hc < 68)  { hh = 33;       ww = hc - 34; }
    else if (hc < 100) { hh = hc - 67;  ww = 0; }
    else               { hh = hc - 99;  ww = 33; }
    uint4* dst = (uint4*)(xh + ((size_t)((b*34 + hh)*34 + ww))*2048);
    dst[tid] = make_uint4(0u, 0u, 0u, 0u);
    return;
  }
  if (bid < PREP_TX + PREP_W + PREP_WH + PREP_HALO + PREP_MAXG) {  // ---- maxg (b,g)
    const int p = bid - (PREP_TX + PREP_W + PREP_WH + PREP_HALO);
    const int b = p / NG, g = p - b*NG;
    const float4 gp = *(const float4*)(gtb + ((size_t)b*NG + g)*4);
    float m = 0.f;
#pragma unroll
    for (int j = 0; j < 36; ++j)
      m = fmaxf(m, iou_one(anc_of(tid + j*256), gp));
#pragma unroll
    for (int o = 32; o > 0; o >>= 1) m = fmaxf(m, __shfl_xor(m, o));
    if ((tid & 63) == 0) red[tid >> 6] = m;
    __syncthreads();
    if (tid == 0)
      maxg[b*NG + g] = __float_as_uint(fmaxf(fmaxf(red[0], red[1]), fmaxf(red[2], red[3])));
    return;
  }
  if (tid < 2) sums[tid] = 0.f;
  else if (tid == 2) *ctr = 0u;
}

// ---------------- conv 3x3 as implicit GEMM, bf16 MFMA, XCD-swizzled ----------------
__global__ __launch_bounds__(256, 4) void k_conv_gemm(const unsigned short* __restrict__ xh,
                                                      const unsigned short* __restrict__ wt,
                                                      unsigned short* __restrict__ hidp,
                                                      int csplit, int ksh) {
  __shared__ unsigned short As[128*64] __attribute__((aligned(16)));
  __shared__ unsigned short Bs[128*64] __attribute__((aligned(16)));
  const int t = threadIdx.x;
  const int L = blockIdx.x;
  const int kz = L & ((1 << ksh) - 1);
  const int rem = L >> ksh;
  const int tileM = rem & 31, tileN = rem >> 5;
  const int b = tileM >> 3, h0 = (tileM & 7) << 2;
  const int o0 = tileN << 7;
  const int wv = t >> 6, lane = t & 63;
  const int wm = wv >> 1, wn = wv & 1;
  const int quad = lane >> 4, l16 = lane & 15;
  const int c_base = kz * csplit;

  floatx4 acc[4][4];
#pragma unroll
  for (int mt = 0; mt < 4; ++mt)
#pragma unroll
    for (int nt = 0; nt < 4; ++nt)
      acc[mt][nt] = (floatx4){0.f, 0.f, 0.f, 0.f};

  const int lr = lane >> 3, pos = lane & 7;
  int gA[4], gB[4];
#pragma unroll
  for (int j = 0; j < 4; ++j) {
    const int row = wv*32 + j*8 + lr;
    const int sd = (pos - row) & 7;                   // seg swizzle (0 conflicts, measured)
    const int hh = h0 + (row >> 5) + 1, ww = (row & 31) + 1;
    gA[j] = ((b*34 + hh)*34 + ww)*2048 + c_base + sd*8;
    gB[j] = (o0 + row)*2048 + c_base + sd*8;
  }

  for (int g = 0; g < 9; ++g) {
    const int dsp = ((g/3 - 1)*34 + (g%3 - 1)) * 2048;
    const unsigned short* wgp = wt + (size_t)g*NHID*NC;
    for (int c0 = 0; c0 < csplit; c0 += 64) {
#pragma unroll
      for (int j = 0; j < 4; ++j) {
        gload16(xh + gA[j] + dsp + c0, As + (wv*32 + j*8)*64);
        gload16(wgp + gB[j] + c0,      Bs + (wv*32 + j*8)*64);
      }
      __syncthreads();
#pragma unroll
      for (int sub = 0; sub < 2; ++sub) {
        const int ps = ((sub*4 + quad) + l16) & 7;
        bf16x8 af[4], bw[4];
#pragma unroll
        for (int mt = 0; mt < 4; ++mt)
          af[mt] = *(const bf16x8*)(As + (wm*64 + mt*16 + l16)*64 + ps*8);
#pragma unroll
        for (int nt = 0; nt < 4; ++nt)
          bw[nt] = *(const bf16x8*)(Bs + (wn*64 + nt*16 + l16)*64 + ps*8);
#pragma unroll
        for (int mt = 0; mt < 4; ++mt)
#pragma unroll
          for (int nt = 0; nt < 4; ++nt)
            acc[mt][nt] = __builtin_amdgcn_mfma_f32_16x16x32_bf16(af[mt], bw[nt], acc[mt][nt], 0, 0, 0);
      }
      __syncthreads();
    }
  }
  unsigned short* hp = hidp + (size_t)kz*NM*NHID;
#pragma unroll
  for (int mt = 0; mt < 4; ++mt) {
    const int m = tileM*128 + wm*64 + mt*16 + quad*4;   // D: row = quad*4+reg
#pragma unroll
    for (int nt = 0; nt < 4; ++nt) {
      const int o = o0 + wn*64 + nt*16 + l16;           // D: col = lane&15
#pragma unroll
      for (int r = 0; r < 4; ++r)
        hp[(size_t)(m + r)*NHID + o] = f2bf(acc[mt][nt][r]);
    }
  }
}

__device__ __forceinline__ float softplusf(float z) {
  return fmaxf(z, 0.f) + log1pf(expf(-fabsf(z)));
}
__device__ __forceinline__ float sl1f(float d) {
  const float ad = fabsf(d);
  return ad < 1.f ? 0.5f*d*d : ad - 0.5f;
}

// ---------------- heads GEMM (register fragments, no inner barriers) + assignment ----------------
__global__ __launch_bounds__(256) void k_heads_assign(const unsigned short* __restrict__ hidp,
                                                      const float* __restrict__ b1,
                                                      const unsigned short* __restrict__ wh,
                                                      const float* __restrict__ hb,
                                                      const float* __restrict__ gtb,
                                                      const unsigned int* __restrict__ maxg,
                                                      float* __restrict__ out,
                                                      float* __restrict__ sums,
                                                      unsigned int* __restrict__ ctr,
                                                      int nsplit) {
  __shared__ float red[4][16][48];
  __shared__ float hl[16][49];
  __shared__ float4 gt_s[20];
  __shared__ float  mg_s[20];
  const int t = threadIdx.x;
  const int bid = blockIdx.x;
  const int b = bid >> 6, pix0 = (bid & 63) << 4;

  if (t < 20) {
    gt_s[t] = *(const float4*)(gtb + ((size_t)b*NG + t)*4);
    mg_s[t] = __uint_as_float(maxg[b*NG + t]);
  }

  const int wv = t >> 6, lane = t & 63;
  const int quad = lane >> 4, l16 = lane & 15;
  floatx4 acc[3];
#pragma unroll
  for (int nt = 0; nt < 3; ++nt) acc[nt] = (floatx4){0.f, 0.f, 0.f, 0.f};

  const int m = bid*16 + l16;                 // A row (global hid row)
#pragma unroll
  for (int kk = 0; kk < 4; ++kk) {
    const int ch0 = wv*128 + kk*32 + quad*8;  // this lane's 8 channels
    float s[8] = {0.f,0.f,0.f,0.f,0.f,0.f,0.f,0.f};
    const size_t gi = (size_t)m*NHID + ch0;
    for (int sp = 0; sp < nsplit; ++sp) {
      const uint4 v = *(const uint4*)(hidp + (size_t)sp*NM*NHID + gi);
      s[0] += __uint_as_float(v.x << 16); s[1] += __uint_as_float(v.x & 0xffff0000u);
      s[2] += __uint_as_float(v.y << 16); s[3] += __uint_as_float(v.y & 0xffff0000u);
      s[4] += __uint_as_float(v.z << 16); s[5] += __uint_as_float(v.z & 0xffff0000u);
      s[6] += __uint_as_float(v.w << 16); s[7] += __uint_as_float(v.w & 0xffff0000u);
    }
    union { unsigned short u[8]; bf16x8 v; } af;
#pragma unroll
    for (int e = 0; e < 8; ++e)
      af.u[e] = f2bf(fmaxf(s[e] + b1[ch0 + e], 0.f));
#pragma unroll
    for (int nt = 0; nt < 3; ++nt) {
      const bf16x8 bf = *(const bf16x8*)(wh + (size_t)(nt*16 + l16)*NHID + ch0);
      acc[nt] = __builtin_amdgcn_mfma_f32_16x16x32_bf16(af.v, bf, acc[nt], 0, 0, 0);
    }
  }
  // cross-wave K reduce: D row = quad*4+r, col = l16 (per m89 layout)
#pragma unroll
  for (int nt = 0; nt < 3; ++nt)
#pragma unroll
    for (int r = 0; r < 4; ++r)
      red[wv][quad*4 + r][nt*16 + l16] = acc[nt][r];
  __syncthreads();
#pragma unroll
  for (int j = 0; j < 3; ++j) {
    const int idx = t + j*256;                // 768 = 16*48 entries
    const int i = idx / 48, c = idx - i*48;
    hl[i][c] = red[0][i][c] + red[1][i][c] + red[2][i][c] + red[3][i][c] + hb[c];
  }
  __syncthreads();

  // ---- assignment, losses, proposals for this block's 144 anchors ----
  float cs = 0.f, rs = 0.f;
  if (t < 144) {
    const int pixL = t / 9, a = t - pixL*9;
    const int pix = pix0 + pixL;
    const int n = pix*9 + a;
    const int idx = b*NANC + n;
    const Anc A = anc_of(n);

    float mx = -1.f; int gi = 0; bool pos = false;
    for (int g = 0; g < NG; ++g) {
      const float v = iou_one(A, gt_s[g]);    // bit-identical to prep-maxg
      const float mg = mg_s[g];
      pos = pos || (v > 0.7f) || ((v == mg) && (mg > 1e-8f));
      if (v > mx) { mx = v; gi = g; }
    }
    const bool neg = (mx < 0.3f) && !pos;
    const float posf = pos ? 1.f : 0.f;

    const float conf = hl[pixL][a];
    const float of0 = hl[pixL][9 + a*4 + 0];
    const float of1 = hl[pixL][9 + a*4 + 1];
    const float of2 = hl[pixL][9 + a*4 + 2];
    const float of3 = hl[pixL][9 + a*4 + 3];

    if (pos) cs = softplusf(-conf);
    else if (neg) cs = softplusf(conf);

    const float acx = (A.x1 + A.x2)*0.5f, acy = (A.y1 + A.y2)*0.5f;
    const float aw = A.x2 - A.x1, ah = A.y2 - A.y1;
    if (pos) {
      const float4 gp = gt_s[gi];
      const float gx1 = gp.x*0.03125f, gy1 = gp.y*0.03125f;
      const float gx2 = gp.z*0.03125f, gy2 = gp.w*0.03125f;
      const float gcx = (gx1+gx2)*0.5f, gcy = (gy1+gy2)*0.5f;
      const float gw = gx2-gx1, gh = gy2-gy1;
      const float t0 = (gcx-acx)/(aw+1e-8f), t1 = (gcy-acy)/(ah+1e-8f);
      const float t2 = logf((gw+1e-8f)/(aw+1e-8f)), t3 = logf((gh+1e-8f)/(ah+1e-8f));
      rs = sl1f(of0-t0) + sl1f(of1-t1) + sl1f(of2-t2) + sl1f(of3-t3);
    }

    const float pcx = acx + of0*aw, pcy = acy + of1*ah;
    const float pw = aw*expf(of2), ph = ah*expf(of3);
    float* op = out + 1 + (size_t)idx*4;
    op[0] = (pcx - pw*0.5f)*posf;
    op[1] = (pcy - ph*0.5f)*posf;
    op[2] = (pcx + pw*0.5f)*posf;
    op[3] = (pcy + ph*0.5f)*posf;
    out[1 + 4*(size_t)NB*NANC + idx] = posf;
  }
#pragma unroll
  for (int o = 32; o > 0; o >>= 1) { cs += __shfl_xor(cs, o); rs += __shfl_xor(rs, o); }
  if ((t & 63) == 0) { atomicAdd(&sums[0], cs); atomicAdd(&sums[1], rs); }

  __syncthreads();
  if (t == 0) {
    __threadfence();
    const unsigned int c = atomicAdd(ctr, 1u);
    if (c == 255u) {                          // 256 blocks total
      __threadfence();
      const float fcs = atomicAdd(&sums[0], 0.f);
      const float frs = atomicAdd(&sums[1], 0.f);
      out[0] = fcs*0.25f + 5.f*(frs*0.25f);   // w_conf*cls/B + w_reg*reg/B
    }
  }
}

extern "C" void kernel_launch(void* const* d_in, const int* in_sizes, int n_in,
                              void* d_out, int out_size, void* d_ws, size_t ws_size,
                              hipStream_t stream) {
  const float* x   = (const float*)d_in[0];
  const float* gtb = (const float*)d_in[1];
  // d_in[2] = gt_classes (unused by the loss)
  const float* w1  = (const float*)d_in[3];
  const float* b1  = (const float*)d_in[4];
  const float* cw  = (const float*)d_in[5];
  const float* cb  = (const float*)d_in[6];
  const float* rw  = (const float*)d_in[7];
  const float* rb  = (const float*)d_in[8];
  float* out = (float*)d_out;
  char* ws = (char*)d_ws;

  unsigned short* xh    = (unsigned short*)(ws + OFF_XH);
  unsigned short* wt    = (unsigned short*)(ws + OFF_WT);
  unsigned short* wh    = (unsigned short*)(ws + OFF_WH);
  float*          hb    = (float*)(ws + OFF_HB);
  unsigned int*   maxg  = (unsigned int*)(ws + OFF_MAXG);
  float*          sums  = (float*)(ws + OFF_SUMS);
  unsigned int*   ctr   = (unsigned int*)(ws + OFF_CTR);
  unsigned short* hidp  = (unsigned short*)(ws + OFF_HIDP);

  int nsplit = 8, ksh = 3;
  while (nsplit > 1 && OFF_HIDP + (size_t)nsplit*NM*NHID*2 > ws_size) { nsplit >>= 1; --ksh; }
  const int csplit = NC / nsplit;

  k_prep<<<PREP_NBLK, 256, 0, stream>>>(x, w1, cw, cb, rw, rb, gtb, xh, wt, wh, hb, maxg, sums, ctr);
  k_conv_gemm<<<128*nsplit, 256, 0, stream>>>(xh, wt, hidp, csplit, ksh);
  k_heads_assign<<<256, 256, 0, stream>>>(hidp, b1, wh, hb, gtb, maxg, out, sums, ctr, nsplit);
}